// Round 12
// baseline (71.229 us; speedup 1.0000x reference)
//
#include <hip/hip_runtime.h>
#include <hip/hip_bf16.h>
#include <stdint.h>

// ---------------------------------------------------------------------------
// Problem constants
// ---------------------------------------------------------------------------
#define KA 22500            // anchors
#define NI 32               // images
#define MG 50               // gt boxes per image
#define NK (NI * KA)        // 720000 labels
#define HNK (NK / 2)
#define COEFF_OFF NK
#define IDX_OFF (NK * 5)
#define MAXFG 128
#define TOTALA 256
#define NBUCK 4096
#define SELCAP 1024
#define K1A 512             // anchors per k1f block (2 per thread)
#define K1CH ((KA + K1A - 1) / K1A)   // 44 chunks
#define NBW 704             // fg/promoted bitmap words per row (22528 bits)
#define K3T 1024
#define K3W (K3T / 64)

#define THREEFRY_PARTITIONABLE 1

// ---------------------------------------------------------------------------
// Threefry-2x32 (matches jax._src.prng exactly)
// ---------------------------------------------------------------------------
__host__ __device__ __forceinline__ uint32_t rotl32(uint32_t v, int r) {
  return (v << r) | (v >> (32 - r));
}

__host__ __device__ __forceinline__ void threefry2x32(uint32_t k0, uint32_t k1,
                                                      uint32_t x0, uint32_t x1,
                                                      uint32_t& o0, uint32_t& o1) {
  uint32_t k2 = k0 ^ k1 ^ 0x1BD11BDAu;
  x0 += k0; x1 += k1;
  x0 += x1; x1 = rotl32(x1, 13); x1 ^= x0;
  x0 += x1; x1 = rotl32(x1, 15); x1 ^= x0;
  x0 += x1; x1 = rotl32(x1, 26); x1 ^= x0;
  x0 += x1; x1 = rotl32(x1, 6);  x1 ^= x0;
  x0 += k1; x1 += k2 + 1u;
  x0 += x1; x1 = rotl32(x1, 17); x1 ^= x0;
  x0 += x1; x1 = rotl32(x1, 29); x1 ^= x0;
  x0 += x1; x1 = rotl32(x1, 16); x1 ^= x0;
  x0 += x1; x1 = rotl32(x1, 24); x1 ^= x0;
  x0 += k2; x1 += k0 + 2u;
  x0 += x1; x1 = rotl32(x1, 13); x1 ^= x0;
  x0 += x1; x1 = rotl32(x1, 15); x1 ^= x0;
  x0 += x1; x1 = rotl32(x1, 26); x1 ^= x0;
  x0 += x1; x1 = rotl32(x1, 6);  x1 ^= x0;
  x0 += k0; x1 += k1 + 3u;
  x0 += x1; x1 = rotl32(x1, 17); x1 ^= x0;
  x0 += x1; x1 = rotl32(x1, 29); x1 ^= x0;
  x0 += x1; x1 = rotl32(x1, 16); x1 ^= x0;
  x0 += x1; x1 = rotl32(x1, 24); x1 ^= x0;
  x0 += k1; x1 += k2 + 4u;
  x0 += x1; x1 = rotl32(x1, 13); x1 ^= x0;
  x0 += x1; x1 = rotl32(x1, 15); x1 ^= x0;
  x0 += x1; x1 = rotl32(x1, 26); x1 ^= x0;
  x0 += x1; x1 = rotl32(x1, 6);  x1 ^= x0;
  x0 += k2; x1 += k0 + 5u;
  o0 = x0; o1 = x1;
}

__device__ __forceinline__ uint32_t rand_m23(uint32_t c0, uint32_t c1, uint32_t j) {
#if THREEFRY_PARTITIONABLE
  uint32_t o0, o1;
  threefry2x32(c0, c1, 0u, j, o0, o1);
  return (o0 ^ o1) >> 9;
#else
  uint32_t o0, o1;
  if (j < (uint32_t)HNK) {
    threefry2x32(c0, c1, j, j + (uint32_t)HNK, o0, o1);
    return o0 >> 9;
  }
  threefry2x32(c0, c1, j - (uint32_t)HNK, j, o0, o1);
  return o1 >> 9;
#endif
}

// ---------------------------------------------------------------------------
// IoU with prefolded +1 (a2p = z+1, a4p = w+1) and v_rcp. 13 VALU ops.
// k1_fused and k3's abox rescan use THIS EXACT function + the same
// per-box prep, so bits(v)==bits(colmax) is internally consistent.
// ---------------------------------------------------------------------------
__device__ __forceinline__ float iou_m(float ax, float ay, float a2p, float a4p,
                                       float areaA, float gx, float gy,
                                       float g2p, float g4p, float areaG) {
#pragma clang fp contract(off)
  float ix1 = fmaxf(ax, gx);
  float iy1 = fmaxf(ay, gy);
  float ex = fminf(a2p, g2p);
  float ey = fminf(a4p, g4p);
  float iw = fmaxf(ex - ix1, 0.0f);
  float ih = fmaxf(ey - iy1, 0.0f);
  float inter = iw * ih;
  float u = (areaA + areaG) - inter;
  return inter * __builtin_amdgcn_rcpf(u);   // union >= ~289, no edge cases
}

// per-anchor epilogue: provisional label (sans abox), coeffs, idx
__device__ __forceinline__ void write_anchor(int n, int k, float4 a, float rb,
                                             int rm, const float4* __restrict__ gb,
                                             float* __restrict__ out_lbl,
                                             float4* __restrict__ out_coeff,
                                             float* __restrict__ out_idx) {
  out_lbl[n * KA + k] = (rb >= 0.7f) ? 1.0f : (rb < 0.3f ? 0.0f : -1.0f);
  {
#pragma clang fp contract(off)
    float4 g = gb[rm];
    float aw = a.z - a.x + 1.0f, ah = a.w - a.y + 1.0f;
    float ax = a.x + 0.5f * aw, ay = a.y + 0.5f * ah;
    float gw = g.z - g.x + 1.0f, gh = g.w - g.y + 1.0f;
    float gx = g.x + 0.5f * gw, gy = g.y + 0.5f * gh;
    float4 c;
    c.x = (gx - ax) / aw;
    c.y = (gy - ay) / ah;
    c.z = logf(gw / aw);
    c.w = logf(gh / ah);
    out_coeff[n * KA + k] = c;
  }
  if (n == 0) out_idx[k] = (float)k;
}

// ---------------------------------------------------------------------------
// K1F: single pass over 36M IoUs. 2 anchors/thread. Column maxima via
// 64-slot LDS atomicMax (2-way bank alias = free) + conflict-free per-wave
// reduce to colpart. Threshold-fg bitmap (fgbit) via ballot, fg partials.
// ---------------------------------------------------------------------------
__global__ __launch_bounds__(256) void k1_fused(const float4* __restrict__ a4,
                                                const float4* __restrict__ gt4,
                                                float* __restrict__ out_lbl,
                                                float4* __restrict__ out_coeff,
                                                float* __restrict__ colpart,
                                                uint32_t* __restrict__ fgpart,
                                                uint32_t* __restrict__ fgbit,
                                                float* __restrict__ out_idx) {
  int n = blockIdx.y;
  int tid = threadIdx.x;
  int lane = tid & 63;
  int wv = tid >> 6;
  int base = blockIdx.x * K1A;
  int ka = base + tid;
  int kb = base + 256 + tid;
  bool vb = kb < KA;
  int kbc = vb ? kb : KA - 1;

  __shared__ uint32_t colpk[MG * 64];  // 12.8 KB
  __shared__ uint32_t s_fg;
  for (int i = tid; i < MG * 64; i += 256) colpk[i] = 0u;
  if (tid == 0) s_fg = 0u;
  __syncthreads();

  float4 A = a4[ka];
  float4 B = a4[kbc];
  float a2pA = A.z + 1.0f, a4pA = A.w + 1.0f;
  float areaA = (a2pA - A.x) * (a4pA - A.y);
  float a2pB = B.z + 1.0f, a4pB = B.w + 1.0f;
  float areaB = (a2pB - B.x) * (a4pB - B.y);
  const float4* gb = gt4 + n * MG;

  float rbA = -1.0f, rbB = -1.0f;
  int rmA = 0, rmB = 0;
  int slot = tid & 63;

  for (int c = 0; c < 5; ++c) {
    float gx[10], gy[10], g2p[10], g4p[10], gA[10];
#pragma unroll
    for (int i = 0; i < 10; ++i) {
      float4 g = gb[c * 10 + i];       // uniform -> s_load
      gx[i] = g.x; gy[i] = g.y;
      g2p[i] = g.z + 1.0f; g4p[i] = g.w + 1.0f;
      gA[i] = (g2p[i] - gx[i]) * (g4p[i] - gy[i]);
    }
#pragma unroll
    for (int i = 0; i < 10; ++i) {
      int m = c * 10 + i;
      float v0 = iou_m(A.x, A.y, a2pA, a4pA, areaA,
                       gx[i], gy[i], g2p[i], g4p[i], gA[i]);
      float v1 = iou_m(B.x, B.y, a2pB, a4pB, areaB,
                       gx[i], gy[i], g2p[i], g4p[i], gA[i]);
      if (v0 > rbA) { rbA = v0; rmA = m; }   // first-index argmax (np rule)
      if (v1 > rbB) { rbB = v1; rmB = m; }
      float cmv = fmaxf(v0, v1);
      atomicMax(&colpk[m * 64 + slot], __float_as_uint(cmv));
    }
  }
  __syncthreads();

  // conflict-free column-partial reduce: wave wv handles m = wv, wv+4, ...
  for (int m = wv; m < MG; m += 4) {
    uint32_t v = colpk[m * 64 + lane];
    v = max(v, (uint32_t)__shfl_down(v, 32));
    v = max(v, (uint32_t)__shfl_down(v, 16));
    v = max(v, (uint32_t)__shfl_down(v, 8));
    v = max(v, (uint32_t)__shfl_down(v, 4));
    v = max(v, (uint32_t)__shfl_down(v, 2));
    v = max(v, (uint32_t)__shfl_down(v, 1));
    if (lane == 0)
      colpart[(n * MG + m) * K1CH + blockIdx.x] = __uint_as_float(v);
  }

  write_anchor(n, ka, A, rbA, rmA, gb, out_lbl, out_coeff, out_idx);
  if (vb) write_anchor(n, kb, B, rbB, rmB, gb, out_lbl, out_coeff, out_idx);

  // threshold-fg bitmap + partial count (race-free inputs for k3)
  bool fgA = rbA >= 0.7f;
  bool fgB = vb && (rbB >= 0.7f);
  uint64_t balA = __ballot(fgA);
  uint64_t balB = __ballot(fgB);
  if (lane == 0) {
    uint32_t w0 = (uint32_t)(base / 32) + wv * 2;       // A anchors
    fgbit[n * NBW + w0] = (uint32_t)balA;
    fgbit[n * NBW + w0 + 1] = (uint32_t)(balA >> 32);
    uint32_t w1 = (uint32_t)(base / 32) + 8 + wv * 2;   // B anchors
    fgbit[n * NBW + w1] = (uint32_t)balB;
    fgbit[n * NBW + w1 + 1] = (uint32_t)(balB >> 32);
    atomicAdd(&s_fg, (uint32_t)(__popcll(balA) + __popcll(balB)));
  }
  __syncthreads();
  if (tid == 0) fgpart[n * K1CH + blockIdx.x] = s_fg;
}

// ---------------------------------------------------------------------------
// K3: abox promotion (folded in) + exact T-th order statistic + final labels.
// Grid (NI,2). Deterministic & race-free:
//  - promoted bitmap + promo count derived only from k1f outputs
//  - histogram match booleans invariant under sibling block's label writes
//  - final label locations single-writer (phase0: eff-fg; phase1: eff-bg)
// ---------------------------------------------------------------------------
__global__ __launch_bounds__(K3T) void k3_select(const float4* __restrict__ a4,
                                                 const float4* __restrict__ gt4,
                                                 float* __restrict__ lbl,
                                                 const float* __restrict__ colpart,
                                                 const uint32_t* __restrict__ fgpart,
                                                 const uint32_t* __restrict__ fgbit,
                                                 uint32_t k10, uint32_t k11,
                                                 uint32_t k20, uint32_t k21) {
  __shared__ uint32_t hist[NBUCK];               // 16 KB
  __shared__ alignas(16) uint32_t mcache[KA];    // 90 KB
  __shared__ uint32_t colm[SELCAP];
  __shared__ uint32_t colk[SELCAP];
  __shared__ uint32_t pbm[NBW];                  // promoted bitmap, 2.8 KB
  __shared__ float cms[MG];
  __shared__ uint32_t wtot[K3W];
  __shared__ uint32_t s_nf, s_promo, ccnt;
  __shared__ int sB;
  __shared__ uint32_t sR;
  __shared__ uint64_t s_theta;

  int n = blockIdx.x;
  int phase = blockIdx.y;
  int tid = threadIdx.x;
  int lane = tid & 63;
  int wv = tid >> 6;
  float* lb = lbl + n * KA;

  uint32_t c0 = phase ? k20 : k10;
  uint32_t c1 = phase ? k21 : k11;

  for (int i = tid; i < NBUCK; i += K3T) hist[i] = 0u;
  for (int i = tid; i < NBW; i += K3T) pbm[i] = 0u;
  if (tid == 0) { ccnt = 0u; sB = -1; s_promo = 0u; s_theta = ~0ull; }
  if (wv == 0) {                       // threshold-fg total from 44 partials
    uint32_t v = (lane < K1CH) ? fgpart[n * K1CH + lane] : 0u;
    v += __shfl_down(v, 32);
    v += __shfl_down(v, 16);
    v += __shfl_down(v, 8);
    v += __shfl_down(v, 4);
    v += __shfl_down(v, 2);
    v += __shfl_down(v, 1);
    if (lane == 0) s_nf = v;
  }
  // column maxima: wave per m, lane per chunk
  for (int m = wv; m < MG; m += K3W) {
    float v = (lane < K1CH) ? colpart[(n * MG + m) * K1CH + lane] : 0.0f;
    v = fmaxf(v, __shfl_down(v, 32));
    v = fmaxf(v, __shfl_down(v, 16));
    v = fmaxf(v, __shfl_down(v, 8));
    v = fmaxf(v, __shfl_down(v, 4));
    v = fmaxf(v, __shfl_down(v, 2));
    v = fmaxf(v, __shfl_down(v, 1));
    if (lane == 0) cms[m] = v;
  }
  __syncthreads();

  // abox rescan: wave per m; only winning chunks (partial == colmax)
  for (int m = wv; m < MG; m += K3W) {
    uint32_t cmb = __float_as_uint(cms[m]);
    float4 g = gt4[n * MG + m];
    float gxx = g.x, gyy = g.y;
    float g2p = g.z + 1.0f, g4p = g.w + 1.0f;
    float gA = (g2p - gxx) * (g4p - gyy);
    float cpv = (lane < K1CH) ? colpart[(n * MG + m) * K1CH + lane] : -1.0f;
    uint64_t winners = __ballot(lane < K1CH && __float_as_uint(cpv) == cmb);
    while (winners) {
      int c = __ffsll((long long)winners) - 1;
      winners &= winners - 1;
#pragma unroll
      for (int r = 0; r < K1A / 64; ++r) {
        int k = c * K1A + r * 64 + lane;
        if (k < KA) {
          float4 a = a4[k];
          float a2p = a.z + 1.0f, a4p = a.w + 1.0f;
          float areaA = (a2p - a.x) * (a4p - a.y);
          float v = iou_m(a.x, a.y, a2p, a4p, areaA, gxx, gyy, g2p, g4p, gA);
          if (__float_as_uint(v) == cmb) {
            uint32_t bit = 1u << (k & 31);
            uint32_t old = atomicOr(&pbm[k >> 5], bit);
            if (!(old & bit) && !((fgbit[n * NBW + (k >> 5)] >> (k & 31)) & 1u))
              atomicAdd(&s_promo, 1u);
          }
        }
      }
    }
  }
  __syncthreads();
  uint32_t nf = s_nf + s_promo;        // |eff_fg|, exact & deterministic

  // histogram + m23 cache over EFFECTIVE match set
  const float4* lb4 = (const float4*)lb;
  for (int q = tid; q < KA / 4; q += K3T) {
    float4 lv = lb4[q];
    uint32_t pw = pbm[q >> 3];         // 4 consecutive k share one word
    uint32_t base_j = (uint32_t)(n * KA + q * 4);
    float lab[4] = {lv.x, lv.y, lv.z, lv.w};
    uint32_t mm[4];
#pragma unroll
    for (int j = 0; j < 4; ++j) {
      int k = q * 4 + j;
      bool pm = (pw >> (k & 31)) & 1u;
      bool match = phase == 0 ? (lab[j] == 1.0f || pm)
                              : (lab[j] == 0.0f && !pm);
      uint32_t m = 0xFFFFFFFFu;
      if (match) {
        m = rand_m23(c0, c1, base_j + j);
        atomicAdd(&hist[m >> 11], 1u);
      }
      mm[j] = m;
    }
    uint4 st; st.x = mm[0]; st.y = mm[1]; st.z = mm[2]; st.w = mm[3];
    ((uint4*)mcache)[q] = st;
  }
  __syncthreads();

  // block scan over 4-bucket chunks
  const int CPB = NBUCK / K3T;
  int base = tid * CPB;
  uint32_t csum = 0;
#pragma unroll
  for (int i = 0; i < CPB; ++i) csum += hist[base + i];
  uint32_t x = csum;
#pragma unroll
  for (int d = 1; d < 64; d <<= 1) {
    uint32_t y = __shfl_up(x, d, 64);
    if (lane >= d) x += y;
  }
  if (lane == 63) wtot[wv] = x;
  __syncthreads();
  uint32_t woff = 0;
  for (int w = 0; w < wv; ++w) woff += wtot[w];
  uint32_t incl = x + woff;
  uint32_t excl = incl - csum;
  uint32_t total = 0;
#pragma unroll
  for (int w = 0; w < K3W; ++w) total += wtot[w];

  uint32_t numfg = nf < (uint32_t)MAXFG ? nf : (uint32_t)MAXFG;
  uint32_t T = phase == 0 ? (uint32_t)MAXFG : (uint32_t)TOTALA - numfg;

  if (total > T) {                     // block-uniform condition
    if (excl < T && T <= incl) {
      uint32_t cum = excl;
      for (int i = 0; i < CPB; ++i) {
        uint32_t h = hist[base + i];
        if (cum + h >= T) { sB = base + i; sR = T - cum; break; }
        cum += h;
      }
    }
    __syncthreads();

    int b = sB;
    for (int q = tid; q < KA / 4; q += K3T) {
      uint4 mm = ((const uint4*)mcache)[q];
      uint32_t marr[4] = {mm.x, mm.y, mm.z, mm.w};
#pragma unroll
      for (int j = 0; j < 4; ++j) {
        if ((int)(marr[j] >> 11) == b) {
          uint32_t i = atomicAdd(&ccnt, 1u);
          if (i < SELCAP) { colm[i] = marr[j]; colk[i] = (uint32_t)(q * 4 + j); }
        }
      }
    }
    __syncthreads();

    uint32_t C = ccnt < (uint32_t)SELCAP ? ccnt : (uint32_t)SELCAP;
    uint32_t r = sR;
    for (uint32_t c = tid; c < C; c += K3T) {
      uint64_t key = ((uint64_t)colm[c] << 32) | (uint64_t)colk[c];
      uint32_t less = 0;
      for (uint32_t j = 0; j < C; ++j) {
        uint64_t kj = ((uint64_t)colm[j] << 32) | (uint64_t)colk[j];
        less += (kj < key) ? 1u : 0u;
      }
      if (less == r - 1u) s_theta = key;
    }
    __syncthreads();
  }

  // final labels: every match-set anchor written (kept value or -1); mids
  // keep k1f's value; promoted anchors get their 1.0 here (phase 0).
  uint64_t th = s_theta;
  float keepv = phase == 0 ? 1.0f : 0.0f;
  for (int q = tid; q < KA / 4; q += K3T) {
    uint4 mm = ((const uint4*)mcache)[q];
    uint32_t marr[4] = {mm.x, mm.y, mm.z, mm.w};
#pragma unroll
    for (int j = 0; j < 4; ++j) {
      if (marr[j] != 0xFFFFFFFFu) {
        uint64_t key = ((uint64_t)marr[j] << 32) | (uint32_t)(q * 4 + j);
        lb[q * 4 + j] = (key <= th) ? keepv : -1.0f;
      }
    }
  }
}

// ---------------------------------------------------------------------------
// Launch (2 kernels)
// ---------------------------------------------------------------------------
extern "C" void kernel_launch(void* const* d_in, const int* in_sizes, int n_in,
                              void* d_out, int out_size, void* d_ws, size_t ws_size,
                              hipStream_t stream) {
  const float* anchors = (const float*)d_in[0];   // [22500,4] f32
  const float* gt = (const float*)d_in[1];        // [32,50,4] f32
  float* out_f = (float*)d_out;
  float* out_lbl = out_f;                         // [32,22500]
  float4* out_coeff = (float4*)(out_f + COEFF_OFF);
  float* out_idx = out_f + IDX_OFF;               // [22500]

  // ws: colpart f32[32*50*44] @0 (281600B) | fgpart u32[32*44] @281600 (5632B)
  //     | fgbit u32[32*704] @287232 (90112B)  -> ~377 KB total
  float* colpart = (float*)d_ws;
  uint32_t* fgpart = (uint32_t*)((char*)d_ws + 281600);
  uint32_t* fgbit = (uint32_t*)((char*)d_ws + 287232);

  uint32_t k10, k11, k20, k21;
#if THREEFRY_PARTITIONABLE
  threefry2x32(0u, 42u, 0u, 0u, k10, k11);
  threefry2x32(0u, 42u, 0u, 1u, k20, k21);
#else
  uint32_t a0, a1, b0, b1;
  threefry2x32(0u, 42u, 0u, 2u, a0, a1);
  threefry2x32(0u, 42u, 1u, 3u, b0, b1);
  k10 = a0; k11 = b0;
  k20 = a1; k21 = b1;
#endif

  k1_fused<<<dim3(K1CH, NI), 256, 0, stream>>>((const float4*)anchors,
                                               (const float4*)gt, out_lbl,
                                               out_coeff, colpart, fgpart,
                                               fgbit, out_idx);
  k3_select<<<dim3(NI, 2), K3T, 0, stream>>>((const float4*)anchors,
                                             (const float4*)gt, out_lbl,
                                             colpart, fgpart, fgbit,
                                             k10, k11, k20, k21);
}

// Round 13
// 66.504 us; speedup vs baseline: 1.0711x; 1.0711x over previous
//
#include <hip/hip_runtime.h>
#include <hip/hip_bf16.h>
#include <stdint.h>

// ---------------------------------------------------------------------------
// Problem constants
// ---------------------------------------------------------------------------
#define KA 22500            // anchors
#define NI 32               // images
#define MG 50               // gt boxes per image
#define NK (NI * KA)        // 720000 labels
#define HNK (NK / 2)
#define COEFF_OFF NK
#define IDX_OFF (NK * 5)
#define MAXFG 128
#define TOTALA 256
#define NBUCK 4096
#define SELCAP 1024
#define K1A 512             // anchors per k1f block (2 per thread)
#define K1CH ((KA + K1A - 1) / K1A)   // 44 chunks
#define K3T 1024
#define K3W (K3T / 64)

#define THREEFRY_PARTITIONABLE 1

// ---------------------------------------------------------------------------
// Threefry-2x32 (matches jax._src.prng exactly)
// ---------------------------------------------------------------------------
__host__ __device__ __forceinline__ uint32_t rotl32(uint32_t v, int r) {
  return (v << r) | (v >> (32 - r));
}

__host__ __device__ __forceinline__ void threefry2x32(uint32_t k0, uint32_t k1,
                                                      uint32_t x0, uint32_t x1,
                                                      uint32_t& o0, uint32_t& o1) {
  uint32_t k2 = k0 ^ k1 ^ 0x1BD11BDAu;
  x0 += k0; x1 += k1;
  x0 += x1; x1 = rotl32(x1, 13); x1 ^= x0;
  x0 += x1; x1 = rotl32(x1, 15); x1 ^= x0;
  x0 += x1; x1 = rotl32(x1, 26); x1 ^= x0;
  x0 += x1; x1 = rotl32(x1, 6);  x1 ^= x0;
  x0 += k1; x1 += k2 + 1u;
  x0 += x1; x1 = rotl32(x1, 17); x1 ^= x0;
  x0 += x1; x1 = rotl32(x1, 29); x1 ^= x0;
  x0 += x1; x1 = rotl32(x1, 16); x1 ^= x0;
  x0 += x1; x1 = rotl32(x1, 24); x1 ^= x0;
  x0 += k2; x1 += k0 + 2u;
  x0 += x1; x1 = rotl32(x1, 13); x1 ^= x0;
  x0 += x1; x1 = rotl32(x1, 15); x1 ^= x0;
  x0 += x1; x1 = rotl32(x1, 26); x1 ^= x0;
  x0 += x1; x1 = rotl32(x1, 6);  x1 ^= x0;
  x0 += k0; x1 += k1 + 3u;
  x0 += x1; x1 = rotl32(x1, 17); x1 ^= x0;
  x0 += x1; x1 = rotl32(x1, 29); x1 ^= x0;
  x0 += x1; x1 = rotl32(x1, 16); x1 ^= x0;
  x0 += x1; x1 = rotl32(x1, 24); x1 ^= x0;
  x0 += k1; x1 += k2 + 4u;
  x0 += x1; x1 = rotl32(x1, 13); x1 ^= x0;
  x0 += x1; x1 = rotl32(x1, 15); x1 ^= x0;
  x0 += x1; x1 = rotl32(x1, 26); x1 ^= x0;
  x0 += x1; x1 = rotl32(x1, 6);  x1 ^= x0;
  x0 += k2; x1 += k0 + 5u;
  o0 = x0; o1 = x1;
}

__device__ __forceinline__ uint32_t rand_m23(uint32_t c0, uint32_t c1, uint32_t j) {
#if THREEFRY_PARTITIONABLE
  uint32_t o0, o1;
  threefry2x32(c0, c1, 0u, j, o0, o1);
  return (o0 ^ o1) >> 9;
#else
  uint32_t o0, o1;
  if (j < (uint32_t)HNK) {
    threefry2x32(c0, c1, j, j + (uint32_t)HNK, o0, o1);
    return o0 >> 9;
  }
  threefry2x32(c0, c1, j - (uint32_t)HNK, j, o0, o1);
  return o1 >> 9;
#endif
}

// ---------------------------------------------------------------------------
// IoU with prefolded +1 (a2p=z+1, a4p=w+1) and v_rcp: 13 VALU ops.
// k1_fused and k2_abox use THIS EXACT function + identical per-box prep so
// bits(v)==bits(colmax) is internally consistent.
// ---------------------------------------------------------------------------
__device__ __forceinline__ float iou_m(float ax, float ay, float a2p, float a4p,
                                       float areaA, float gx, float gy,
                                       float g2p, float g4p, float areaG) {
#pragma clang fp contract(off)
  float ix1 = fmaxf(ax, gx);
  float iy1 = fmaxf(ay, gy);
  float ex = fminf(a2p, g2p);
  float ey = fminf(a4p, g4p);
  float iw = fmaxf(ex - ix1, 0.0f);
  float ih = fmaxf(ey - iy1, 0.0f);
  float inter = iw * ih;
  float u = (areaA + areaG) - inter;
  return inter * __builtin_amdgcn_rcpf(u);   // union >= ~289, no edge cases
}

// per-anchor epilogue: provisional label (sans abox), coeffs, idx
__device__ __forceinline__ void write_anchor(int n, int k, float4 a, float rb,
                                             int rm, const float4* __restrict__ gb,
                                             float* __restrict__ out_lbl,
                                             float4* __restrict__ out_coeff,
                                             float* __restrict__ out_idx) {
  out_lbl[n * KA + k] = (rb >= 0.7f) ? 1.0f : (rb < 0.3f ? 0.0f : -1.0f);
  {
#pragma clang fp contract(off)
    float4 g = gb[rm];
    float aw = a.z - a.x + 1.0f, ah = a.w - a.y + 1.0f;
    float ax = a.x + 0.5f * aw, ay = a.y + 0.5f * ah;
    float gw = g.z - g.x + 1.0f, gh = g.w - g.y + 1.0f;
    float gx = g.x + 0.5f * gw, gy = g.y + 0.5f * gh;
    float4 c;
    c.x = (gx - ax) / aw;
    c.y = (gy - ay) / ah;
    c.z = logf(gw / aw);
    c.w = logf(gh / ah);
    out_coeff[n * KA + k] = c;
  }
  if (n == 0) out_idx[k] = (float)k;
}

// ---------------------------------------------------------------------------
// K1F: single pass over 36M IoUs. 2 anchors/thread, prefolded IoU (13 ops).
// Column maxima via 64-slot LDS atomicMax (2-way alias = free) +
// conflict-free per-wave reduce to colpart. fg partials; fgcorr init.
// ---------------------------------------------------------------------------
__global__ __launch_bounds__(256) void k1_fused(const float4* __restrict__ a4,
                                                const float4* __restrict__ gt4,
                                                float* __restrict__ out_lbl,
                                                float4* __restrict__ out_coeff,
                                                float* __restrict__ colpart,
                                                uint32_t* __restrict__ fgpart,
                                                uint32_t* __restrict__ fgcorr,
                                                float* __restrict__ out_idx) {
  int n = blockIdx.y;
  int tid = threadIdx.x;
  int lane = tid & 63;
  int wv = tid >> 6;
  int base = blockIdx.x * K1A;
  int ka = base + tid;
  int kb = base + 256 + tid;
  bool vb = kb < KA;
  int kbc = vb ? kb : KA - 1;

  __shared__ uint32_t colpk[MG * 64];  // 12.8 KB
  __shared__ uint32_t s_fg;
  for (int i = tid; i < MG * 64; i += 256) colpk[i] = 0u;
  if (tid == 0) {
    s_fg = 0u;
    if (blockIdx.x == 0) fgcorr[n] = 0u;   // k2_abox runs after (stream order)
  }
  __syncthreads();

  float4 A = a4[ka];
  float4 B = a4[kbc];
  float a2pA = A.z + 1.0f, a4pA = A.w + 1.0f;
  float areaA = (a2pA - A.x) * (a4pA - A.y);
  float a2pB = B.z + 1.0f, a4pB = B.w + 1.0f;
  float areaB = (a2pB - B.x) * (a4pB - B.y);
  const float4* gb = gt4 + n * MG;

  float rbA = -1.0f, rbB = -1.0f;
  int rmA = 0, rmB = 0;
  int slot = tid & 63;

  for (int c = 0; c < 5; ++c) {
    float gx[10], gy[10], g2p[10], g4p[10], gA[10];
#pragma unroll
    for (int i = 0; i < 10; ++i) {
      float4 g = gb[c * 10 + i];       // uniform -> s_load
      gx[i] = g.x; gy[i] = g.y;
      g2p[i] = g.z + 1.0f; g4p[i] = g.w + 1.0f;
      gA[i] = (g2p[i] - gx[i]) * (g4p[i] - gy[i]);
    }
#pragma unroll
    for (int i = 0; i < 10; ++i) {
      int m = c * 10 + i;
      float v0 = iou_m(A.x, A.y, a2pA, a4pA, areaA,
                       gx[i], gy[i], g2p[i], g4p[i], gA[i]);
      float v1 = iou_m(B.x, B.y, a2pB, a4pB, areaB,
                       gx[i], gy[i], g2p[i], g4p[i], gA[i]);
      if (v0 > rbA) { rbA = v0; rmA = m; }   // first-index argmax (np rule)
      if (v1 > rbB) { rbB = v1; rmB = m; }
      float cmv = fmaxf(v0, v1);       // clamped dup kb: same anchor, harmless
      atomicMax(&colpk[m * 64 + slot], __float_as_uint(cmv));
    }
  }
  __syncthreads();

  // conflict-free column-partial reduce: wave wv handles m = wv, wv+4, ...
  for (int m = wv; m < MG; m += 4) {
    uint32_t v = colpk[m * 64 + lane];
    v = max(v, (uint32_t)__shfl_down(v, 32));
    v = max(v, (uint32_t)__shfl_down(v, 16));
    v = max(v, (uint32_t)__shfl_down(v, 8));
    v = max(v, (uint32_t)__shfl_down(v, 4));
    v = max(v, (uint32_t)__shfl_down(v, 2));
    v = max(v, (uint32_t)__shfl_down(v, 1));
    if (lane == 0)
      colpart[(n * MG + m) * K1CH + blockIdx.x] = __uint_as_float(v);
  }

  write_anchor(n, ka, A, rbA, rmA, gb, out_lbl, out_coeff, out_idx);
  if (vb) write_anchor(n, kb, B, rbB, rmB, gb, out_lbl, out_coeff, out_idx);

  bool fgA = rbA >= 0.7f;
  bool fgB = vb && (rbB >= 0.7f);
  uint32_t cnt = (uint32_t)__popcll(__ballot(fgA)) +
                 (uint32_t)__popcll(__ballot(fgB));
  if ((tid & 63) == 0) atomicAdd(&s_fg, cnt);
  __syncthreads();
  if (tid == 0) fgpart[n * K1CH + blockIdx.x] = s_fg;
}

// ---------------------------------------------------------------------------
// K2_ABOX (standalone again -- r12 showed folding it into k3 costs 22us):
// per (m,n): global colmax = max of 44 chunk partials (uniform s_load);
// rescan ONLY winning chunks (~512 IoUs) and promote every anchor with
// bits(v)==bits(colmax). atomicExch dedupes; fgcorr counts promotions.
// 1600 blocks -> latency well hidden.
// ---------------------------------------------------------------------------
__global__ __launch_bounds__(256) void k2_abox(const float4* __restrict__ a4,
                                               const float4* __restrict__ gt4,
                                               const float* __restrict__ colpart,
                                               float* __restrict__ out_lbl,
                                               uint32_t* __restrict__ fgcorr) {
  int m = blockIdx.x;
  int n = blockIdx.y;
  int tid = threadIdx.x;
  const float* cp = colpart + (n * MG + m) * K1CH;   // uniform -> s_load

  float cm = cp[0];
#pragma unroll
  for (int j = 1; j < K1CH; ++j) cm = fmaxf(cm, cp[j]);
  uint32_t cmb = __float_as_uint(cm);

  float4 g = gt4[n * MG + m];
  float gxx = g.x, gyy = g.y;
  float g2p = g.z + 1.0f, g4p = g.w + 1.0f;
  float gA = (g2p - gxx) * (g4p - gyy);

  for (int c = 0; c < K1CH; ++c) {
    if (__float_as_uint(cp[c]) == cmb) {       // winning chunk (usually 1)
#pragma unroll
      for (int h = 0; h < 2; ++h) {
        int k = c * K1A + h * 256 + tid;
        if (k < KA) {
          float4 a = a4[k];
          float a2p = a.z + 1.0f, a4p = a.w + 1.0f;
          float areaA = (a2p - a.x) * (a4p - a.y);
          float v = iou_m(a.x, a.y, a2p, a4p, areaA, gxx, gyy, g2p, g4p, gA);
          if (__float_as_uint(v) == cmb) {
            float old = atomicExch(&out_lbl[n * KA + k], 1.0f);
            if (old != 1.0f) atomicAdd(&fgcorr[n], 1u);  // exactly-once count
          }
        }
      }
    }
  }
}

// ---------------------------------------------------------------------------
// K3: exact T-th order statistic per (row, phase) + in-place label rewrite.
// 1024 threads, vectorized passes (the r10/r11 version that measured ~15us).
// ---------------------------------------------------------------------------
__global__ __launch_bounds__(K3T) void k3_select(float* __restrict__ lbl,
                                                 const uint32_t* __restrict__ fgpart,
                                                 const uint32_t* __restrict__ fgcorr,
                                                 uint32_t k10, uint32_t k11,
                                                 uint32_t k20, uint32_t k21) {
  __shared__ uint32_t hist[NBUCK];               // 16 KB
  __shared__ alignas(16) uint32_t mcache[KA];    // 90 KB
  __shared__ uint32_t colm[SELCAP];
  __shared__ uint32_t colk[SELCAP];
  __shared__ uint32_t wtot[K3W];
  __shared__ uint32_t s_nf;
  __shared__ uint32_t ccnt;
  __shared__ int sB;
  __shared__ uint32_t sR;
  __shared__ uint64_t s_theta;

  int n = blockIdx.x;
  int phase = blockIdx.y;
  int tid = threadIdx.x;
  int lane = tid & 63;
  int wv = tid >> 6;
  float* lb = lbl + n * KA;

  float match = phase ? 0.0f : 1.0f;
  uint32_t c0 = phase ? k20 : k10;
  uint32_t c1 = phase ? k21 : k11;

  for (int i = tid; i < NBUCK; i += K3T) hist[i] = 0u;
  if (tid == 0) { ccnt = 0u; sB = -1; }
  if (wv == 0) {                       // fg total: 44 partials + corr
    uint32_t v = (lane < K1CH) ? fgpart[n * K1CH + lane] : 0u;
    v += __shfl_down(v, 32);
    v += __shfl_down(v, 16);
    v += __shfl_down(v, 8);
    v += __shfl_down(v, 4);
    v += __shfl_down(v, 2);
    v += __shfl_down(v, 1);
    if (lane == 0) s_nf = v + fgcorr[n];
  }
  __syncthreads();
  uint32_t nf = s_nf;

  // 1. histogram + m23 cache (float4 label loads, uint4 LDS stores)
  const float4* lb4 = (const float4*)lb;
  for (int q = tid; q < KA / 4; q += K3T) {
    float4 lv = lb4[q];
    uint4 st;
    uint32_t base_j = (uint32_t)(n * KA + q * 4);
    float lab[4] = {lv.x, lv.y, lv.z, lv.w};
    uint32_t mm[4];
#pragma unroll
    for (int j = 0; j < 4; ++j) {
      uint32_t m = 0xFFFFFFFFu;
      if (lab[j] == match) {
        m = rand_m23(c0, c1, base_j + j);
        atomicAdd(&hist[m >> 11], 1u);
      }
      mm[j] = m;
    }
    st.x = mm[0]; st.y = mm[1]; st.z = mm[2]; st.w = mm[3];
    ((uint4*)mcache)[q] = st;
  }
  __syncthreads();

  // 2. block scan over 4-bucket chunks
  const int CPB = NBUCK / K3T;
  int base = tid * CPB;
  uint32_t csum = 0;
#pragma unroll
  for (int i = 0; i < CPB; ++i) csum += hist[base + i];
  uint32_t x = csum;
#pragma unroll
  for (int d = 1; d < 64; d <<= 1) {
    uint32_t y = __shfl_up(x, d, 64);
    if (lane >= d) x += y;
  }
  if (lane == 63) wtot[wv] = x;
  __syncthreads();
  uint32_t woff = 0;
  for (int w = 0; w < wv; ++w) woff += wtot[w];
  uint32_t incl = x + woff;
  uint32_t excl = incl - csum;
  uint32_t total = 0;
#pragma unroll
  for (int w = 0; w < K3W; ++w) total += wtot[w];

  uint32_t numfg = nf < (uint32_t)MAXFG ? nf : (uint32_t)MAXFG;
  uint32_t T = phase == 0 ? (uint32_t)MAXFG : (uint32_t)TOTALA - numfg;

  if (total <= T) return;              // keep all matching

  if (excl < T && T <= incl) {
    uint32_t cum = excl;
    for (int i = 0; i < CPB; ++i) {
      uint32_t h = hist[base + i];
      if (cum + h >= T) { sB = base + i; sR = T - cum; break; }
      cum += h;
    }
  }
  __syncthreads();

  // 3. collect candidates in the crossing bucket
  int b = sB;
  for (int q = tid; q < KA / 4; q += K3T) {
    uint4 mm = ((const uint4*)mcache)[q];
    uint32_t marr[4] = {mm.x, mm.y, mm.z, mm.w};
#pragma unroll
    for (int j = 0; j < 4; ++j) {
      if ((int)(marr[j] >> 11) == b) {
        uint32_t i = atomicAdd(&ccnt, 1u);
        if (i < SELCAP) { colm[i] = marr[j]; colk[i] = (uint32_t)(q * 4 + j); }
      }
    }
  }
  __syncthreads();

  // 4. parallel rank selection (keys distinct)
  uint32_t C = ccnt < (uint32_t)SELCAP ? ccnt : (uint32_t)SELCAP;
  uint32_t r = sR;
  for (uint32_t c = tid; c < C; c += K3T) {
    uint64_t key = ((uint64_t)colm[c] << 32) | (uint64_t)colk[c];
    uint32_t less = 0;
    for (uint32_t j = 0; j < C; ++j) {
      uint64_t kj = ((uint64_t)colm[j] << 32) | (uint64_t)colk[j];
      less += (kj < key) ? 1u : 0u;
    }
    if (less == r - 1u) s_theta = key;
  }
  __syncthreads();

  // 5. drop matching anchors beyond theta
  uint64_t th = s_theta;
  for (int q = tid; q < KA / 4; q += K3T) {
    uint4 mm = ((const uint4*)mcache)[q];
    uint32_t marr[4] = {mm.x, mm.y, mm.z, mm.w};
#pragma unroll
    for (int j = 0; j < 4; ++j) {
      if (marr[j] != 0xFFFFFFFFu) {
        uint64_t key = ((uint64_t)marr[j] << 32) | (uint32_t)(q * 4 + j);
        if (key > th) lb[q * 4 + j] = -1.0f;
      }
    }
  }
}

// ---------------------------------------------------------------------------
// Launch (3 kernels: fused-IoU -> abox-scatter -> sampling)
// ---------------------------------------------------------------------------
extern "C" void kernel_launch(void* const* d_in, const int* in_sizes, int n_in,
                              void* d_out, int out_size, void* d_ws, size_t ws_size,
                              hipStream_t stream) {
  const float* anchors = (const float*)d_in[0];   // [22500,4] f32
  const float* gt = (const float*)d_in[1];        // [32,50,4] f32
  float* out_f = (float*)d_out;
  float* out_lbl = out_f;                         // [32,22500]
  float4* out_coeff = (float4*)(out_f + COEFF_OFF);
  float* out_idx = out_f + IDX_OFF;               // [22500]

  // ws: colpart f32[32*50*44] @0 (281600B) | fgpart u32[32*44] @281600 (5632B)
  //     | fgcorr u32[32] @287232
  float* colpart = (float*)d_ws;
  uint32_t* fgpart = (uint32_t*)((char*)d_ws + 281600);
  uint32_t* fgcorr = (uint32_t*)((char*)d_ws + 287232);

  uint32_t k10, k11, k20, k21;
#if THREEFRY_PARTITIONABLE
  threefry2x32(0u, 42u, 0u, 0u, k10, k11);
  threefry2x32(0u, 42u, 0u, 1u, k20, k21);
#else
  uint32_t a0, a1, b0, b1;
  threefry2x32(0u, 42u, 0u, 2u, a0, a1);
  threefry2x32(0u, 42u, 1u, 3u, b0, b1);
  k10 = a0; k11 = b0;
  k20 = a1; k21 = b1;
#endif

  k1_fused<<<dim3(K1CH, NI), 256, 0, stream>>>((const float4*)anchors,
                                               (const float4*)gt, out_lbl,
                                               out_coeff, colpart, fgpart,
                                               fgcorr, out_idx);
  k2_abox<<<dim3(MG, NI), 256, 0, stream>>>((const float4*)anchors,
                                            (const float4*)gt, colpart,
                                            out_lbl, fgcorr);
  k3_select<<<dim3(NI, 2), K3T, 0, stream>>>(out_lbl, fgpart, fgcorr,
                                             k10, k11, k20, k21);
}

// Round 14
// 61.947 us; speedup vs baseline: 1.1498x; 1.0736x over previous
//
#include <hip/hip_runtime.h>
#include <hip/hip_bf16.h>
#include <stdint.h>

// ---------------------------------------------------------------------------
// Problem constants
// ---------------------------------------------------------------------------
#define KA 22500            // anchors
#define NI 32               // images
#define MG 50               // gt boxes per image
#define NK (NI * KA)        // 720000 labels
#define HNK (NK / 2)
#define COEFF_OFF NK
#define IDX_OFF (NK * 5)
#define MAXFG 128
#define TOTALA 256
#define NBUCK 4096
#define SELCAP 1024
#define K1A 512             // anchors per k1f block (2 per thread)
#define K1CH ((KA + K1A - 1) / K1A)   // 44 chunks
#define KSLICE (KA / MG)    // 450: per-(m,n) m23 slice in k2_abox
#define K3T 1024
#define K3W (K3T / 64)

#define THREEFRY_PARTITIONABLE 1

// ---------------------------------------------------------------------------
// Threefry-2x32 (matches jax._src.prng exactly)
// ---------------------------------------------------------------------------
__host__ __device__ __forceinline__ uint32_t rotl32(uint32_t v, int r) {
  return (v << r) | (v >> (32 - r));
}

__host__ __device__ __forceinline__ void threefry2x32(uint32_t k0, uint32_t k1,
                                                      uint32_t x0, uint32_t x1,
                                                      uint32_t& o0, uint32_t& o1) {
  uint32_t k2 = k0 ^ k1 ^ 0x1BD11BDAu;
  x0 += k0; x1 += k1;
  x0 += x1; x1 = rotl32(x1, 13); x1 ^= x0;
  x0 += x1; x1 = rotl32(x1, 15); x1 ^= x0;
  x0 += x1; x1 = rotl32(x1, 26); x1 ^= x0;
  x0 += x1; x1 = rotl32(x1, 6);  x1 ^= x0;
  x0 += k1; x1 += k2 + 1u;
  x0 += x1; x1 = rotl32(x1, 17); x1 ^= x0;
  x0 += x1; x1 = rotl32(x1, 29); x1 ^= x0;
  x0 += x1; x1 = rotl32(x1, 16); x1 ^= x0;
  x0 += x1; x1 = rotl32(x1, 24); x1 ^= x0;
  x0 += k2; x1 += k0 + 2u;
  x0 += x1; x1 = rotl32(x1, 13); x1 ^= x0;
  x0 += x1; x1 = rotl32(x1, 15); x1 ^= x0;
  x0 += x1; x1 = rotl32(x1, 26); x1 ^= x0;
  x0 += x1; x1 = rotl32(x1, 6);  x1 ^= x0;
  x0 += k0; x1 += k1 + 3u;
  x0 += x1; x1 = rotl32(x1, 17); x1 ^= x0;
  x0 += x1; x1 = rotl32(x1, 29); x1 ^= x0;
  x0 += x1; x1 = rotl32(x1, 16); x1 ^= x0;
  x0 += x1; x1 = rotl32(x1, 24); x1 ^= x0;
  x0 += k1; x1 += k2 + 4u;
  x0 += x1; x1 = rotl32(x1, 13); x1 ^= x0;
  x0 += x1; x1 = rotl32(x1, 15); x1 ^= x0;
  x0 += x1; x1 = rotl32(x1, 26); x1 ^= x0;
  x0 += x1; x1 = rotl32(x1, 6);  x1 ^= x0;
  x0 += k2; x1 += k0 + 5u;
  o0 = x0; o1 = x1;
}

__device__ __forceinline__ uint32_t rand_m23(uint32_t c0, uint32_t c1, uint32_t j) {
#if THREEFRY_PARTITIONABLE
  uint32_t o0, o1;
  threefry2x32(c0, c1, 0u, j, o0, o1);
  return (o0 ^ o1) >> 9;
#else
  uint32_t o0, o1;
  if (j < (uint32_t)HNK) {
    threefry2x32(c0, c1, j, j + (uint32_t)HNK, o0, o1);
    return o0 >> 9;
  }
  threefry2x32(c0, c1, j - (uint32_t)HNK, j, o0, o1);
  return o1 >> 9;
#endif
}

// ---------------------------------------------------------------------------
// IoU with prefolded +1 (a2p=z+1, a4p=w+1) and v_rcp: 13 VALU ops.
// k1_fused and k2_abox use THIS EXACT function + identical per-box prep so
// bits(v)==bits(colmax) is internally consistent.
// ---------------------------------------------------------------------------
__device__ __forceinline__ float iou_m(float ax, float ay, float a2p, float a4p,
                                       float areaA, float gx, float gy,
                                       float g2p, float g4p, float areaG) {
#pragma clang fp contract(off)
  float ix1 = fmaxf(ax, gx);
  float iy1 = fmaxf(ay, gy);
  float ex = fminf(a2p, g2p);
  float ey = fminf(a4p, g4p);
  float iw = fmaxf(ex - ix1, 0.0f);
  float ih = fmaxf(ey - iy1, 0.0f);
  float inter = iw * ih;
  float u = (areaA + areaG) - inter;
  return inter * __builtin_amdgcn_rcpf(u);   // union >= ~289, no edge cases
}

// per-anchor epilogue: provisional label (sans abox), coeffs, idx
__device__ __forceinline__ void write_anchor(int n, int k, float4 a, float rb,
                                             int rm, const float4* __restrict__ gb,
                                             float* __restrict__ out_lbl,
                                             float4* __restrict__ out_coeff,
                                             float* __restrict__ out_idx) {
  out_lbl[n * KA + k] = (rb >= 0.7f) ? 1.0f : (rb < 0.3f ? 0.0f : -1.0f);
  {
#pragma clang fp contract(off)
    float4 g = gb[rm];
    float aw = a.z - a.x + 1.0f, ah = a.w - a.y + 1.0f;
    float ax = a.x + 0.5f * aw, ay = a.y + 0.5f * ah;
    float gw = g.z - g.x + 1.0f, gh = g.w - g.y + 1.0f;
    float gx = g.x + 0.5f * gw, gy = g.y + 0.5f * gh;
    float4 c;
    c.x = (gx - ax) / aw;
    c.y = (gy - ay) / ah;
    c.z = logf(gw / aw);
    c.w = logf(gh / ah);
    out_coeff[n * KA + k] = c;
  }
  if (n == 0) out_idx[k] = (float)k;
}

// ---------------------------------------------------------------------------
// K1F: single pass over 36M IoUs (unchanged from r13 -- r12/r13 showed its
// internals are not the lever; leave it stable).
// ---------------------------------------------------------------------------
__global__ __launch_bounds__(256) void k1_fused(const float4* __restrict__ a4,
                                                const float4* __restrict__ gt4,
                                                float* __restrict__ out_lbl,
                                                float4* __restrict__ out_coeff,
                                                float* __restrict__ colpart,
                                                uint32_t* __restrict__ fgpart,
                                                uint32_t* __restrict__ fgcorr,
                                                float* __restrict__ out_idx) {
  int n = blockIdx.y;
  int tid = threadIdx.x;
  int lane = tid & 63;
  int wv = tid >> 6;
  int base = blockIdx.x * K1A;
  int ka = base + tid;
  int kb = base + 256 + tid;
  bool vb = kb < KA;
  int kbc = vb ? kb : KA - 1;

  __shared__ uint32_t colpk[MG * 64];  // 12.8 KB
  __shared__ uint32_t s_fg;
  for (int i = tid; i < MG * 64; i += 256) colpk[i] = 0u;
  if (tid == 0) {
    s_fg = 0u;
    if (blockIdx.x == 0) fgcorr[n] = 0u;   // k2_abox runs after (stream order)
  }
  __syncthreads();

  float4 A = a4[ka];
  float4 B = a4[kbc];
  float a2pA = A.z + 1.0f, a4pA = A.w + 1.0f;
  float areaA = (a2pA - A.x) * (a4pA - A.y);
  float a2pB = B.z + 1.0f, a4pB = B.w + 1.0f;
  float areaB = (a2pB - B.x) * (a4pB - B.y);
  const float4* gb = gt4 + n * MG;

  float rbA = -1.0f, rbB = -1.0f;
  int rmA = 0, rmB = 0;
  int slot = tid & 63;

  for (int c = 0; c < 5; ++c) {
    float gx[10], gy[10], g2p[10], g4p[10], gA[10];
#pragma unroll
    for (int i = 0; i < 10; ++i) {
      float4 g = gb[c * 10 + i];       // uniform -> s_load
      gx[i] = g.x; gy[i] = g.y;
      g2p[i] = g.z + 1.0f; g4p[i] = g.w + 1.0f;
      gA[i] = (g2p[i] - gx[i]) * (g4p[i] - gy[i]);
    }
#pragma unroll
    for (int i = 0; i < 10; ++i) {
      int m = c * 10 + i;
      float v0 = iou_m(A.x, A.y, a2pA, a4pA, areaA,
                       gx[i], gy[i], g2p[i], g4p[i], gA[i]);
      float v1 = iou_m(B.x, B.y, a2pB, a4pB, areaB,
                       gx[i], gy[i], g2p[i], g4p[i], gA[i]);
      if (v0 > rbA) { rbA = v0; rmA = m; }   // first-index argmax (np rule)
      if (v1 > rbB) { rbB = v1; rmB = m; }
      float cmv = fmaxf(v0, v1);       // clamped dup kb: same anchor, harmless
      atomicMax(&colpk[m * 64 + slot], __float_as_uint(cmv));
    }
  }
  __syncthreads();

  // conflict-free column-partial reduce: wave wv handles m = wv, wv+4, ...
  for (int m = wv; m < MG; m += 4) {
    uint32_t v = colpk[m * 64 + lane];
    v = max(v, (uint32_t)__shfl_down(v, 32));
    v = max(v, (uint32_t)__shfl_down(v, 16));
    v = max(v, (uint32_t)__shfl_down(v, 8));
    v = max(v, (uint32_t)__shfl_down(v, 4));
    v = max(v, (uint32_t)__shfl_down(v, 2));
    v = max(v, (uint32_t)__shfl_down(v, 1));
    if (lane == 0)
      colpart[(n * MG + m) * K1CH + blockIdx.x] = __uint_as_float(v);
  }

  write_anchor(n, ka, A, rbA, rmA, gb, out_lbl, out_coeff, out_idx);
  if (vb) write_anchor(n, kb, B, rbB, rmB, gb, out_lbl, out_coeff, out_idx);

  bool fgA = rbA >= 0.7f;
  bool fgB = vb && (rbB >= 0.7f);
  uint32_t cnt = (uint32_t)__popcll(__ballot(fgA)) +
                 (uint32_t)__popcll(__ballot(fgB));
  if ((tid & 63) == 0) atomicAdd(&s_fg, cnt);
  __syncthreads();
  if (tid == 0) fgpart[n * K1CH + blockIdx.x] = s_fg;
}

// ---------------------------------------------------------------------------
// K2_ABOX + RNG PRODUCER: besides the abox rescan (unchanged), each (m,n)
// block fills the m23 key slices for anchors [m*450,(m+1)*450) -- moving
// 45K threefry/row from k3's 64-block starved regime to this 1600-block
// kernel where they're latency-hidden (~2us chip-wide).
// ---------------------------------------------------------------------------
__global__ __launch_bounds__(256) void k2_abox(const float4* __restrict__ a4,
                                               const float4* __restrict__ gt4,
                                               const float* __restrict__ colpart,
                                               float* __restrict__ out_lbl,
                                               uint32_t* __restrict__ fgcorr,
                                               uint32_t* __restrict__ m23fg,
                                               uint32_t* __restrict__ m23bg,
                                               uint32_t k10, uint32_t k11,
                                               uint32_t k20, uint32_t k21) {
  int m = blockIdx.x;
  int n = blockIdx.y;
  int tid = threadIdx.x;

  // RNG slice first (independent; overlaps the colpart s_loads below)
  for (int i = tid; i < KSLICE; i += 256) {
    int k = m * KSLICE + i;
    uint32_t j = (uint32_t)(n * KA + k);
    m23fg[n * KA + k] = rand_m23(k10, k11, j);
    m23bg[n * KA + k] = rand_m23(k20, k21, j);
  }

  const float* cp = colpart + (n * MG + m) * K1CH;   // uniform -> s_load
  float cm = cp[0];
#pragma unroll
  for (int j = 1; j < K1CH; ++j) cm = fmaxf(cm, cp[j]);
  uint32_t cmb = __float_as_uint(cm);

  float4 g = gt4[n * MG + m];
  float gxx = g.x, gyy = g.y;
  float g2p = g.z + 1.0f, g4p = g.w + 1.0f;
  float gA = (g2p - gxx) * (g4p - gyy);

  for (int c = 0; c < K1CH; ++c) {
    if (__float_as_uint(cp[c]) == cmb) {       // winning chunk (usually 1)
#pragma unroll
      for (int h = 0; h < 2; ++h) {
        int k = c * K1A + h * 256 + tid;
        if (k < KA) {
          float4 a = a4[k];
          float a2p = a.z + 1.0f, a4p = a.w + 1.0f;
          float areaA = (a2p - a.x) * (a4p - a.y);
          float v = iou_m(a.x, a.y, a2p, a4p, areaA, gxx, gyy, g2p, g4p, gA);
          if (__float_as_uint(v) == cmb) {
            float old = atomicExch(&out_lbl[n * KA + k], 1.0f);
            if (old != 1.0f) atomicAdd(&fgcorr[n], 1u);  // exactly-once count
          }
        }
      }
    }
  }
}

// ---------------------------------------------------------------------------
// K3: exact T-th order statistic per (row, phase) + in-place label rewrite.
// Pass 1 now LOADS precomputed m23 keys (uint4) instead of computing
// threefry at 64-block occupancy.
// ---------------------------------------------------------------------------
__global__ __launch_bounds__(K3T) void k3_select(float* __restrict__ lbl,
                                                 const uint32_t* __restrict__ fgpart,
                                                 const uint32_t* __restrict__ fgcorr,
                                                 const uint32_t* __restrict__ m23fg,
                                                 const uint32_t* __restrict__ m23bg) {
  __shared__ uint32_t hist[NBUCK];               // 16 KB
  __shared__ alignas(16) uint32_t mcache[KA];    // 90 KB
  __shared__ uint32_t colm[SELCAP];
  __shared__ uint32_t colk[SELCAP];
  __shared__ uint32_t wtot[K3W];
  __shared__ uint32_t s_nf;
  __shared__ uint32_t ccnt;
  __shared__ int sB;
  __shared__ uint32_t sR;
  __shared__ uint64_t s_theta;

  int n = blockIdx.x;
  int phase = blockIdx.y;
  int tid = threadIdx.x;
  int lane = tid & 63;
  int wv = tid >> 6;
  float* lb = lbl + n * KA;

  float match = phase ? 0.0f : 1.0f;
  const uint32_t* mG = (phase ? m23bg : m23fg) + n * KA;

  for (int i = tid; i < NBUCK; i += K3T) hist[i] = 0u;
  if (tid == 0) { ccnt = 0u; sB = -1; }
  if (wv == 0) {                       // fg total: 44 partials + corr
    uint32_t v = (lane < K1CH) ? fgpart[n * K1CH + lane] : 0u;
    v += __shfl_down(v, 32);
    v += __shfl_down(v, 16);
    v += __shfl_down(v, 8);
    v += __shfl_down(v, 4);
    v += __shfl_down(v, 2);
    v += __shfl_down(v, 1);
    if (lane == 0) s_nf = v + fgcorr[n];
  }
  __syncthreads();
  uint32_t nf = s_nf;

  // 1. histogram + m23 cache (float4 label loads, uint4 key loads)
  const float4* lb4 = (const float4*)lb;
  const uint4* mG4 = (const uint4*)mG;
  for (int q = tid; q < KA / 4; q += K3T) {
    float4 lv = lb4[q];
    uint4 kv = mG4[q];
    float lab[4] = {lv.x, lv.y, lv.z, lv.w};
    uint32_t kk[4] = {kv.x, kv.y, kv.z, kv.w};
    uint32_t mm[4];
#pragma unroll
    for (int j = 0; j < 4; ++j) {
      uint32_t m = 0xFFFFFFFFu;
      if (lab[j] == match) {
        m = kk[j];
        atomicAdd(&hist[m >> 11], 1u);
      }
      mm[j] = m;
    }
    uint4 st; st.x = mm[0]; st.y = mm[1]; st.z = mm[2]; st.w = mm[3];
    ((uint4*)mcache)[q] = st;
  }
  __syncthreads();

  // 2. block scan over 4-bucket chunks
  const int CPB = NBUCK / K3T;
  int base = tid * CPB;
  uint32_t csum = 0;
#pragma unroll
  for (int i = 0; i < CPB; ++i) csum += hist[base + i];
  uint32_t x = csum;
#pragma unroll
  for (int d = 1; d < 64; d <<= 1) {
    uint32_t y = __shfl_up(x, d, 64);
    if (lane >= d) x += y;
  }
  if (lane == 63) wtot[wv] = x;
  __syncthreads();
  uint32_t woff = 0;
  for (int w = 0; w < wv; ++w) woff += wtot[w];
  uint32_t incl = x + woff;
  uint32_t excl = incl - csum;
  uint32_t total = 0;
#pragma unroll
  for (int w = 0; w < K3W; ++w) total += wtot[w];

  uint32_t numfg = nf < (uint32_t)MAXFG ? nf : (uint32_t)MAXFG;
  uint32_t T = phase == 0 ? (uint32_t)MAXFG : (uint32_t)TOTALA - numfg;

  if (total <= T) return;              // keep all matching

  if (excl < T && T <= incl) {
    uint32_t cum = excl;
    for (int i = 0; i < CPB; ++i) {
      uint32_t h = hist[base + i];
      if (cum + h >= T) { sB = base + i; sR = T - cum; break; }
      cum += h;
    }
  }
  __syncthreads();

  // 3. collect candidates in the crossing bucket
  int b = sB;
  for (int q = tid; q < KA / 4; q += K3T) {
    uint4 mm = ((const uint4*)mcache)[q];
    uint32_t marr[4] = {mm.x, mm.y, mm.z, mm.w};
#pragma unroll
    for (int j = 0; j < 4; ++j) {
      if ((int)(marr[j] >> 11) == b) {
        uint32_t i = atomicAdd(&ccnt, 1u);
        if (i < SELCAP) { colm[i] = marr[j]; colk[i] = (uint32_t)(q * 4 + j); }
      }
    }
  }
  __syncthreads();

  // 4. parallel rank selection (keys distinct)
  uint32_t C = ccnt < (uint32_t)SELCAP ? ccnt : (uint32_t)SELCAP;
  uint32_t r = sR;
  for (uint32_t c = tid; c < C; c += K3T) {
    uint64_t key = ((uint64_t)colm[c] << 32) | (uint64_t)colk[c];
    uint32_t less = 0;
    for (uint32_t j = 0; j < C; ++j) {
      uint64_t kj = ((uint64_t)colm[j] << 32) | (uint64_t)colk[j];
      less += (kj < key) ? 1u : 0u;
    }
    if (less == r - 1u) s_theta = key;
  }
  __syncthreads();

  // 5. drop matching anchors beyond theta
  uint64_t th = s_theta;
  for (int q = tid; q < KA / 4; q += K3T) {
    uint4 mm = ((const uint4*)mcache)[q];
    uint32_t marr[4] = {mm.x, mm.y, mm.z, mm.w};
#pragma unroll
    for (int j = 0; j < 4; ++j) {
      if (marr[j] != 0xFFFFFFFFu) {
        uint64_t key = ((uint64_t)marr[j] << 32) | (uint32_t)(q * 4 + j);
        if (key > th) lb[q * 4 + j] = -1.0f;
      }
    }
  }
}

// ---------------------------------------------------------------------------
// Launch (3 kernels)
// ---------------------------------------------------------------------------
extern "C" void kernel_launch(void* const* d_in, const int* in_sizes, int n_in,
                              void* d_out, int out_size, void* d_ws, size_t ws_size,
                              hipStream_t stream) {
  const float* anchors = (const float*)d_in[0];   // [22500,4] f32
  const float* gt = (const float*)d_in[1];        // [32,50,4] f32
  float* out_f = (float*)d_out;
  float* out_lbl = out_f;                         // [32,22500]
  float4* out_coeff = (float4*)(out_f + COEFF_OFF);
  float* out_idx = out_f + IDX_OFF;               // [22500]

  // ws: colpart f32[32*50*44] @0 (281600B) | fgpart u32[32*44] @281600 (5632B)
  //     | fgcorr u32[32] @287232 | m23fg u32[NK] @294912 (2.88MB)
  //     | m23bg u32[NK] @3174912  (total ~6.06MB; ws is ~268MB)
  float* colpart = (float*)d_ws;
  uint32_t* fgpart = (uint32_t*)((char*)d_ws + 281600);
  uint32_t* fgcorr = (uint32_t*)((char*)d_ws + 287232);
  uint32_t* m23fg = (uint32_t*)((char*)d_ws + 294912);
  uint32_t* m23bg = (uint32_t*)((char*)d_ws + 3174912);

  uint32_t k10, k11, k20, k21;
#if THREEFRY_PARTITIONABLE
  threefry2x32(0u, 42u, 0u, 0u, k10, k11);
  threefry2x32(0u, 42u, 0u, 1u, k20, k21);
#else
  uint32_t a0, a1, b0, b1;
  threefry2x32(0u, 42u, 0u, 2u, a0, a1);
  threefry2x32(0u, 42u, 1u, 3u, b0, b1);
  k10 = a0; k11 = b0;
  k20 = a1; k21 = b1;
#endif

  k1_fused<<<dim3(K1CH, NI), 256, 0, stream>>>((const float4*)anchors,
                                               (const float4*)gt, out_lbl,
                                               out_coeff, colpart, fgpart,
                                               fgcorr, out_idx);
  k2_abox<<<dim3(MG, NI), 256, 0, stream>>>((const float4*)anchors,
                                            (const float4*)gt, colpart,
                                            out_lbl, fgcorr, m23fg, m23bg,
                                            k10, k11, k20, k21);
  k3_select<<<dim3(NI, 2), K3T, 0, stream>>>(out_lbl, fgpart, fgcorr,
                                             m23fg, m23bg);
}